// Round 8
// baseline (53.877 us; speedup 1.0000x reference)
//
#include <hip/hip_runtime.h>
#include <hip/hip_bf16.h>
#include <math.h>

#define B 8
#define S 2048
#define IN_DIM 8
#define EMB 512
#define HEADS 8
#define HDIM 64
#define HALF 256
#define NCLS 3
#define NCHUNK 32   // t-chunks of 64
#define CT 64       // timesteps per chunk
#define SINSTRIDE 260  // [t][j] sin table row stride (260%4==0 for float4; lane bank spread uniform)

// workspace layout (float offsets)
#define WS_KQ    0            // [B][HEADS][EMB] (hi half used)        = 32768
#define WS_COEF1 32768        // [B][HEADS][12]  (a[0..7], c0, c1)     = 768
#define WS_PM    33536        // [B][32][HEADS][16] (m,Z,ta,fa[8])     = 32768
#define WS_PS    66304        // [B][32][HEADS][256] S-partials        = 524288
#define WS_POP   590592       // [B][HEADS][EMB] Wo partials           = 32768
#define WS_CTR   623360       // [B] ticket counters (uint)            = 8

// K1: per (b,h): recompute x_last -> q-chunk(h) -> kq[b][h][:] -> coef
__global__ __launch_bounds__(256) void k_head(
    const float* __restrict__ feat, const float* __restrict__ ts,
    const float* __restrict__ Wf, const float* __restrict__ bf,
    const float* __restrict__ Wl, const float* __restrict__ bl,
    const float* __restrict__ Wp, const float* __restrict__ bp,
    const float* __restrict__ Wq, const float* __restrict__ bq,
    const float* __restrict__ Wk, const float* __restrict__ bk,
    float* __restrict__ ws)
{
    const int h = blockIdx.x;
    const int b = blockIdx.y;
    const int bh = b*HEADS + h;
    const int tid = threadIdx.x;
    __shared__ float xl[EMB];
    __shared__ __align__(16) float qc[HDIM];
    __shared__ float kq[EMB];
    __shared__ float red[4][64];
    __shared__ float red10[4][12];

    // phase 0: x at last position
    {
        const float tl = ts[b*S + (S-1)];
        float fv[IN_DIM];
        #pragma unroll
        for (int i = 0; i < IN_DIM; ++i) fv[i] = feat[(b*S + (S-1))*IN_DIM + i];
        #pragma unroll
        for (int r = 0; r < 2; ++r) {
            const int e = tid + r*256;
            float acc = bf[e];
            #pragma unroll
            for (int i = 0; i < IN_DIM; ++i) acc += fv[i]*Wf[i*EMB + e];
            if (r == 0) acc += tl*Wl[e] + bl[e];
            else        acc += __sinf(tl*Wp[e-HALF] + bp[e-HALF]);
            xl[e] = acc;
        }
    }
    __syncthreads();
    // phase 1: q-chunk for this head (4-way split-K)
    {
        const int eo = tid & 63, jq = tid >> 6;
        float acc = (jq == 0) ? bq[h*HDIM + eo] : 0.f;
        #pragma unroll 8
        for (int j = jq*128; j < jq*128 + 128; ++j)
            acc += xl[j]*Wq[j*EMB + h*HDIM + eo];
        red[jq][eo] = acc;
    }
    __syncthreads();
    if (tid < HDIM) qc[tid] = red[0][tid]+red[1][tid]+red[2][tid]+red[3][tid];
    __syncthreads();
    // phase 2: kq[j] = Wk[j, h*64:+64] . qc
    {
        #pragma unroll
        for (int r = 0; r < 2; ++r) {
            const int j = tid + r*256;
            const float4* wr = (const float4*)(Wk + j*EMB + h*HDIM);
            const float4* qv = (const float4*)qc;
            float acc = 0.f;
            #pragma unroll
            for (int k = 0; k < 16; ++k) {
                const float4 w = wr[k], q4 = qv[k];
                acc += w.x*q4.x + w.y*q4.y + w.z*q4.z + w.w*q4.w;
            }
            kq[j] = acc;
            if (j >= HALF) ws[WS_KQ + bh*EMB + j] = acc;
        }
    }
    __syncthreads();
    // phase 3: coef
    {
        float a[IN_DIM] = {0.f,0.f,0.f,0.f,0.f,0.f,0.f,0.f};
        float c0 = 0.f, c1 = 0.f;
        #pragma unroll
        for (int r = 0; r < 2; ++r) {
            const int e = tid + r*256;
            const float kv = kq[e];
            #pragma unroll
            for (int i = 0; i < IN_DIM; ++i) a[i] += Wf[i*EMB + e]*kv;
            c0 += bf[e]*kv;
            if (r == 0) { c0 += bl[e]*kv; c1 += Wl[e]*kv; }
        }
        if (tid < HDIM) c0 += qc[tid]*bk[h*HDIM + tid];
        #pragma unroll
        for (int off = 32; off >= 1; off >>= 1) {
            #pragma unroll
            for (int i = 0; i < IN_DIM; ++i) a[i] += __shfl_xor(a[i], off, 64);
            c0 += __shfl_xor(c0, off, 64);
            c1 += __shfl_xor(c1, off, 64);
        }
        const int wid = tid >> 6, lane = tid & 63;
        if (lane == 0) {
            #pragma unroll
            for (int i = 0; i < IN_DIM; ++i) red10[wid][i] = a[i];
            red10[wid][8] = c0; red10[wid][9] = c1;
        }
        __syncthreads();
        if (tid < 10)
            ws[WS_COEF1 + bh*12 + tid] =
                red10[0][tid]+red10[1][tid]+red10[2][tid]+red10[3][tid];
    }
}

// K2: per (b, 64-t chunk): sin table [t][j] once -> scores(8h, float4 sin reads)
//     -> local softmax stats -> unnormalized S-partials.
__global__ __launch_bounds__(256) void k_part(
    const float* __restrict__ feat, const float* __restrict__ ts,
    const float* __restrict__ Wp, const float* __restrict__ bp,
    const float* __restrict__ tdp, float* __restrict__ ws)
{
    const int c = blockIdx.x;      // 0..31
    const int b = blockIdx.y;
    const int tid = threadIdx.x;   // 256
    const int t0 = c*CT;

    __shared__ __align__(16) float sin_l[CT*SINSTRIDE];  // [t][j]
    __shared__ __align__(16) float kqh[HEADS][256];
    __shared__ __align__(16) float w_l[CT*8];  // [t][h]
    __shared__ float tv_l[CT];
    __shared__ float f_l[CT*9];                // [t][i] stride 9
    __shared__ float cf[96];                   // [h][12]

    if (tid < CT) tv_l[tid] = ts[b*S + t0 + tid];
    for (int idx = tid; idx < CT*IN_DIM; idx += 256) {
        const int tt = idx >> 3, i = idx & 7;
        f_l[tt*9 + i] = feat[(b*S + t0 + tt)*IN_DIM + i];
    }
    for (int idx = tid; idx < HEADS*256; idx += 256)
        ((float*)kqh)[idx] = ws[WS_KQ + (b*HEADS + (idx >> 8))*EMB + HALF + (idx & 255)];
    if (tid < 96) cf[tid] = ws[WS_COEF1 + b*96 + tid];
    const float tl = ts[b*S + (S-1)];
    const float td = tdp[0];
    __syncthreads();

    // phase 1: sin table [t][j] (thread = j)
    {
        const float wj = Wp[tid], bj = bp[tid];
        #pragma unroll 4
        for (int tt = 0; tt < CT; ++tt)
            sin_l[tt*SINSTRIDE + tid] = __sinf(tv_l[tt]*wj + bj);
    }
    __syncthreads();

    // phase 2: scores for (t, h0) and (t, h0+4); sin via float4 row reads
    const int t = tid & 63, h0 = tid >> 6;
    const float tv = tv_l[t];
    float fv[IN_DIM];
    #pragma unroll
    for (int i = 0; i < IN_DIM; ++i) fv[i] = f_l[t*9 + i];
    const float dec = __expf(-td*fabsf(tl - tv));
    float sc[2];
    {
        float acc0 = 0.f, acc1 = 0.f;
        const float4* srow = (const float4*)(sin_l + t*SINSTRIDE);
        const float4* kq0 = (const float4*)&kqh[h0][0];
        const float4* kq1 = (const float4*)&kqh[h0+4][0];
        #pragma unroll 4
        for (int j4 = 0; j4 < 64; ++j4) {
            const float4 sv = srow[j4];
            const float4 ka = kq0[j4], kb = kq1[j4];
            acc0 += sv.x*ka.x + sv.y*ka.y + sv.z*ka.z + sv.w*ka.w;
            acc1 += sv.x*kb.x + sv.y*kb.y + sv.z*kb.z + sv.w*kb.w;
        }
        #pragma unroll
        for (int p = 0; p < 2; ++p) {
            const int h = h0 + p*4;
            float base = cf[h*12+8] + tv*cf[h*12+9];
            #pragma unroll
            for (int i = 0; i < IN_DIM; ++i) base += fv[i]*cf[h*12+i];
            sc[p] = (base + ((p == 0) ? acc0 : acc1))*0.125f*dec;
        }
    }
    // phase 3: per-wave (= per (h,chunk)) local softmax stats
    #pragma unroll
    for (int p = 0; p < 2; ++p) {
        const int h = h0 + p*4;
        float m = sc[p];
        #pragma unroll
        for (int off = 32; off >= 1; off >>= 1) m = fmaxf(m, __shfl_xor(m, off, 64));
        const float w = __expf(sc[p] - m);
        float Z = w, ta = w*tv;
        float fa[IN_DIM];
        #pragma unroll
        for (int i = 0; i < IN_DIM; ++i) fa[i] = w*fv[i];
        #pragma unroll
        for (int off = 32; off >= 1; off >>= 1) {
            Z  += __shfl_xor(Z,  off, 64);
            ta += __shfl_xor(ta, off, 64);
            #pragma unroll
            for (int i = 0; i < IN_DIM; ++i) fa[i] += __shfl_xor(fa[i], off, 64);
        }
        w_l[t*8 + h] = w;
        if (t == 0) {
            float* pm = ws + WS_PM + ((b*NCHUNK + c)*HEADS + h)*16;
            pm[0] = m; pm[1] = Z; pm[2] = ta;
            #pragma unroll
            for (int i = 0; i < IN_DIM; ++i) pm[3+i] = fa[i];
        }
    }
    __syncthreads();
    // phase 4: S_c[h][j] = sum_t w[t][h] * sin[t][j]
    {
        const int j = tid;
        float accS[HEADS] = {0.f,0.f,0.f,0.f,0.f,0.f,0.f,0.f};
        const float4* wv4 = (const float4*)w_l;
        #pragma unroll 4
        for (int tt = 0; tt < CT; ++tt) {
            const float sv = sin_l[tt*SINSTRIDE + j];
            const float4 wa = wv4[tt*2], wb = wv4[tt*2+1];
            accS[0] += wa.x*sv; accS[1] += wa.y*sv; accS[2] += wa.z*sv; accS[3] += wa.w*sv;
            accS[4] += wb.x*sv; accS[5] += wb.y*sv; accS[6] += wb.z*sv; accS[7] += wb.w*sv;
        }
        const int base = WS_PS + ((b*NCHUNK + c)*HEADS)*256 + j;
        #pragma unroll
        for (int h = 0; h < HEADS; ++h) ws[base + h*256] = accS[h];
    }
}

// K3: per (b,h), 512 thr: flash merge -> wx -> Wv gemv (oh chunk) -> Wo partial
//     -> ticket; last block per b runs the tail (op sum -> W1+relu -> W2 -> logits)
__global__ __launch_bounds__(512) void k_owt(
    const float* __restrict__ Wf, const float* __restrict__ bf,
    const float* __restrict__ Wl, const float* __restrict__ bl,
    const float* __restrict__ Wv, const float* __restrict__ bv,
    const float* __restrict__ Wo, const float* __restrict__ bo,
    const float* __restrict__ W1, const float* __restrict__ b1,
    const float* __restrict__ W2, const float* __restrict__ b2,
    float* __restrict__ ws, float* __restrict__ out)
{
    const int h = blockIdx.x;
    const int b = blockIdx.y;
    const int tid = threadIdx.x;
    __shared__ float pmL[NCHUNK][12];
    __shared__ float al[NCHUNK];
    __shared__ float cfL[10];
    __shared__ float wx[EMB];          // reused as opL in tail
    __shared__ float red[8][64];       // reused as redW1[2][256] in tail
    __shared__ __align__(16) float oh_c[HDIM];
    __shared__ float hhL[HALF];
    __shared__ float red3[4][3];
    __shared__ unsigned tick;

    if (tid < NCHUNK*11)
        pmL[tid/11][tid%11] = ws[WS_PM + ((b*NCHUNK + tid/11)*HEADS + h)*16 + tid%11];
    __syncthreads();
    float m = pmL[0][0];
    #pragma unroll 8
    for (int c = 1; c < NCHUNK; ++c) m = fmaxf(m, pmL[c][0]);
    if (tid < NCHUNK) al[tid] = __expf(pmL[tid][0] - m);
    __syncthreads();
    float Z = 0.f;
    #pragma unroll 8
    for (int c = 0; c < NCHUNK; ++c) Z += al[c]*pmL[c][1];
    const float inv = 1.f/Z;
    if (tid < 9) {
        const int k = (tid == 8) ? 2 : 3 + tid;   // ta at [2], fa_i at [3+i]
        float acc = 0.f;
        #pragma unroll 8
        for (int c = 0; c < NCHUNK; ++c) acc += al[c]*pmL[c][k];
        cfL[(tid == 8) ? 8 : tid] = acc*inv;
    }
    __syncthreads();
    // wx assembly: e = tid (0..511)
    {
        const int e = tid;
        float val = bf[e];
        #pragma unroll
        for (int i = 0; i < IN_DIM; ++i) val += cfL[i]*Wf[i*EMB + e];
        if (e < HALF) {
            val += cfL[8]*Wl[e] + bl[e];
        } else {
            const int j = e - HALF;
            float acc = 0.f;
            #pragma unroll 8
            for (int c = 0; c < NCHUNK; ++c)
                acc += al[c]*ws[WS_PS + ((b*NCHUNK + c)*HEADS + h)*256 + j];
            val += acc*inv;
        }
        wx[e] = val;
    }
    __syncthreads();
    // Wv gemv for this head's 64 cols (8-way split-K)
    {
        const int eo = tid & 63, jq = tid >> 6;
        const int e = h*HDIM + eo;
        float acc = 0.f;
        #pragma unroll 8
        for (int j = jq*64; j < jq*64 + 64; ++j)
            acc += wx[j]*Wv[j*EMB + e];
        red[jq][eo] = acc;
    }
    __syncthreads();
    if (tid < 64) {
        float s = 0.f;
        #pragma unroll
        for (int q = 0; q < 8; ++q) s += red[q][tid];
        oh_c[tid] = s + bv[h*HDIM + tid];
    }
    __syncthreads();
    // Wo partial: pop[e] = sum_{d<64} oh_c[d] * Wo[(h*64+d)*EMB + e]
    {
        const int e = tid;
        float acc = 0.f;
        #pragma unroll 8
        for (int d = 0; d < HDIM; ++d)
            acc += oh_c[d]*Wo[(h*HDIM + d)*EMB + e];
        ws[WS_POP + (b*HEADS + h)*EMB + e] = acc;
    }
    // ---- ticket: last block of this b runs the tail ----
    __threadfence();
    if (tid == 0) {
        unsigned* ctr = (unsigned*)(ws + WS_CTR);
        tick = atomicAdd(&ctr[b], 1u);
    }
    __syncthreads();
    if ((tick & 7u) != 7u) return;
    __threadfence();   // acquire: see other blocks' pop writes

    // op = sum_h pop + bo   (reuse wx as opL)
    {
        const int e = tid;
        float acc = bo[e];
        #pragma unroll
        for (int hh = 0; hh < HEADS; ++hh)
            acc += ws[WS_POP + (b*HEADS + hh)*EMB + e];
        wx[e] = acc;
    }
    __syncthreads();
    // W1 + relu (2-way split-K over j)
    {
        float* redW1 = (float*)red;   // [2][256]
        const int mm = tid & 255, jq = tid >> 8;
        float acc = 0.f;
        #pragma unroll 8
        for (int j = jq*256; j < jq*256 + 256; ++j)
            acc += wx[j]*W1[j*HALF + mm];
        redW1[jq*HALF + mm] = acc;
    }
    __syncthreads();
    if (tid < HALF) {
        const float* redW1 = (const float*)red;
        hhL[tid] = fmaxf(redW1[tid] + redW1[HALF + tid] + b1[tid], 0.f);
    }
    __syncthreads();
    // W2: logits
    if (tid < HALF) {
        const float hv = hhL[tid];
        float p0 = hv*W2[tid*NCLS + 0];
        float p1 = hv*W2[tid*NCLS + 1];
        float p2 = hv*W2[tid*NCLS + 2];
        #pragma unroll
        for (int off = 32; off >= 1; off >>= 1) {
            p0 += __shfl_xor(p0, off, 64);
            p1 += __shfl_xor(p1, off, 64);
            p2 += __shfl_xor(p2, off, 64);
        }
        const int wid = tid >> 6;
        if ((tid & 63) == 0) { red3[wid][0] = p0; red3[wid][1] = p1; red3[wid][2] = p2; }
    }
    __syncthreads();
    if (tid < NCLS)
        out[b*NCLS + tid] = red3[0][tid]+red3[1][tid]+red3[2][tid]+red3[3][tid] + b2[tid];
}

extern "C" void kernel_launch(void* const* d_in, const int* in_sizes, int n_in,
                              void* d_out, int out_size, void* d_ws, size_t ws_size,
                              hipStream_t stream)
{
    const float* feat = (const float*)d_in[0];
    const float* ts   = (const float*)d_in[1];
    const float* Wf = (const float*)d_in[2];
    const float* bf = (const float*)d_in[3];
    const float* Wl = (const float*)d_in[4];
    const float* bl = (const float*)d_in[5];
    const float* Wp = (const float*)d_in[6];
    const float* bp = (const float*)d_in[7];
    const float* Wq = (const float*)d_in[8];
    const float* bq = (const float*)d_in[9];
    const float* Wk = (const float*)d_in[10];
    const float* bk = (const float*)d_in[11];
    const float* Wv = (const float*)d_in[12];
    const float* bv = (const float*)d_in[13];
    const float* Wo = (const float*)d_in[14];
    const float* bo = (const float*)d_in[15];
    const float* td = (const float*)d_in[16];
    const float* W1 = (const float*)d_in[17];
    const float* b1 = (const float*)d_in[18];
    const float* W2 = (const float*)d_in[19];
    const float* b2 = (const float*)d_in[20];
    float* ws = (float*)d_ws;
    float* out = (float*)d_out;

    hipLaunchKernelGGL(k_head, dim3(HEADS, B),  dim3(256), 0, stream,
                       feat, ts, Wf, bf, Wl, bl, Wp, bp, Wq, bq, Wk, bk, ws);
    hipLaunchKernelGGL(k_part, dim3(NCHUNK, B), dim3(256), 0, stream,
                       feat, ts, Wp, bp, td, ws);
    hipLaunchKernelGGL(k_owt,  dim3(HEADS, B),  dim3(512), 0, stream,
                       Wf, bf, Wl, bl, Wv, bv, Wo, bo, W1, b1, W2, b2, ws, out);
}

// Round 9
// 42.704 us; speedup vs baseline: 1.2616x; 1.2616x over previous
//
#include <hip/hip_runtime.h>
#include <hip/hip_bf16.h>
#include <math.h>

#define B 8
#define S 2048
#define IN_DIM 8
#define EMB 512
#define HEADS 8
#define HDIM 64
#define HALF 256
#define NCLS 3
#define NCHUNK 32   // t-chunks of 64
#define CT 64       // timesteps per chunk
#define SINSTRIDE 260  // [t][j] row stride; 260/4=65 odd -> float4 reads spread all 8 bank-windows

// workspace layout (float offsets)
#define WS_KQ    0            // [B][HEADS][EMB] (hi half used)        = 32768
#define WS_COEF1 32768        // [B][HEADS][12]  (a[0..7], c0, c1)     = 768
#define WS_PM    33536        // [B][32][HEADS][16] (m,Z,ta,fa[8])     = 32768
#define WS_PS    66304        // [B][32][HEADS][256] S-partials        = 524288
#define WS_POP   590592       // [B][HEADS][EMB] Wo partials           = 32768

// K1: per (b,h): recompute x_last -> q-chunk(h) -> kq[b][h][:] -> coef
__global__ __launch_bounds__(256) void k_head(
    const float* __restrict__ feat, const float* __restrict__ ts,
    const float* __restrict__ Wf, const float* __restrict__ bf,
    const float* __restrict__ Wl, const float* __restrict__ bl,
    const float* __restrict__ Wp, const float* __restrict__ bp,
    const float* __restrict__ Wq, const float* __restrict__ bq,
    const float* __restrict__ Wk, const float* __restrict__ bk,
    float* __restrict__ ws)
{
    const int h = blockIdx.x;
    const int b = blockIdx.y;
    const int bh = b*HEADS + h;
    const int tid = threadIdx.x;
    __shared__ float xl[EMB];
    __shared__ __align__(16) float qc[HDIM];
    __shared__ float kq[EMB];
    __shared__ float red[4][64];
    __shared__ float red10[4][12];

    // phase 0: x at last position
    {
        const float tl = ts[b*S + (S-1)];
        float fv[IN_DIM];
        #pragma unroll
        for (int i = 0; i < IN_DIM; ++i) fv[i] = feat[(b*S + (S-1))*IN_DIM + i];
        #pragma unroll
        for (int r = 0; r < 2; ++r) {
            const int e = tid + r*256;
            float acc = bf[e];
            #pragma unroll
            for (int i = 0; i < IN_DIM; ++i) acc += fv[i]*Wf[i*EMB + e];
            if (r == 0) acc += tl*Wl[e] + bl[e];
            else        acc += __sinf(tl*Wp[e-HALF] + bp[e-HALF]);
            xl[e] = acc;
        }
    }
    __syncthreads();
    // phase 1: q-chunk for this head (4-way split-K)
    {
        const int eo = tid & 63, jq = tid >> 6;
        float acc = (jq == 0) ? bq[h*HDIM + eo] : 0.f;
        #pragma unroll 8
        for (int j = jq*128; j < jq*128 + 128; ++j)
            acc += xl[j]*Wq[j*EMB + h*HDIM + eo];
        red[jq][eo] = acc;
    }
    __syncthreads();
    if (tid < HDIM) qc[tid] = red[0][tid]+red[1][tid]+red[2][tid]+red[3][tid];
    __syncthreads();
    // phase 2: kq[j] = Wk[j, h*64:+64] . qc
    {
        #pragma unroll
        for (int r = 0; r < 2; ++r) {
            const int j = tid + r*256;
            const float4* wr = (const float4*)(Wk + j*EMB + h*HDIM);
            const float4* qv = (const float4*)qc;
            float acc = 0.f;
            #pragma unroll
            for (int k = 0; k < 16; ++k) {
                const float4 w = wr[k], q4 = qv[k];
                acc += w.x*q4.x + w.y*q4.y + w.z*q4.z + w.w*q4.w;
            }
            kq[j] = acc;
            if (j >= HALF) ws[WS_KQ + bh*EMB + j] = acc;
        }
    }
    __syncthreads();
    // phase 3: coef
    {
        float a[IN_DIM] = {0.f,0.f,0.f,0.f,0.f,0.f,0.f,0.f};
        float c0 = 0.f, c1 = 0.f;
        #pragma unroll
        for (int r = 0; r < 2; ++r) {
            const int e = tid + r*256;
            const float kv = kq[e];
            #pragma unroll
            for (int i = 0; i < IN_DIM; ++i) a[i] += Wf[i*EMB + e]*kv;
            c0 += bf[e]*kv;
            if (r == 0) { c0 += bl[e]*kv; c1 += Wl[e]*kv; }
        }
        if (tid < HDIM) c0 += qc[tid]*bk[h*HDIM + tid];
        #pragma unroll
        for (int off = 32; off >= 1; off >>= 1) {
            #pragma unroll
            for (int i = 0; i < IN_DIM; ++i) a[i] += __shfl_xor(a[i], off, 64);
            c0 += __shfl_xor(c0, off, 64);
            c1 += __shfl_xor(c1, off, 64);
        }
        const int wid = tid >> 6, lane = tid & 63;
        if (lane == 0) {
            #pragma unroll
            for (int i = 0; i < IN_DIM; ++i) red10[wid][i] = a[i];
            red10[wid][8] = c0; red10[wid][9] = c1;
        }
        __syncthreads();
        if (tid < 10)
            ws[WS_COEF1 + bh*12 + tid] =
                red10[0][tid]+red10[1][tid]+red10[2][tid]+red10[3][tid];
    }
}

// K2: per (b, 64-t chunk): sin table [t][j] once -> scores(8h, float4 sin reads)
//     -> local softmax stats -> unnormalized S-partials.
__global__ __launch_bounds__(256) void k_part(
    const float* __restrict__ feat, const float* __restrict__ ts,
    const float* __restrict__ Wp, const float* __restrict__ bp,
    const float* __restrict__ tdp, float* __restrict__ ws)
{
    const int c = blockIdx.x;      // 0..31
    const int b = blockIdx.y;
    const int tid = threadIdx.x;   // 256
    const int t0 = c*CT;

    __shared__ __align__(16) float sin_l[CT*SINSTRIDE];  // [t][j]
    __shared__ __align__(16) float kqh[HEADS][256];
    __shared__ __align__(16) float w_l[CT*8];  // [t][h]
    __shared__ float tv_l[CT];
    __shared__ float f_l[CT*9];                // [t][i] stride 9
    __shared__ float cf[96];                   // [h][12]

    if (tid < CT) tv_l[tid] = ts[b*S + t0 + tid];
    for (int idx = tid; idx < CT*IN_DIM; idx += 256) {
        const int tt = idx >> 3, i = idx & 7;
        f_l[tt*9 + i] = feat[(b*S + t0 + tt)*IN_DIM + i];
    }
    for (int idx = tid; idx < HEADS*256; idx += 256)
        ((float*)kqh)[idx] = ws[WS_KQ + (b*HEADS + (idx >> 8))*EMB + HALF + (idx & 255)];
    if (tid < 96) cf[tid] = ws[WS_COEF1 + b*96 + tid];
    const float tl = ts[b*S + (S-1)];
    const float td = tdp[0];
    __syncthreads();

    // phase 1: sin table [t][j] (thread = j)
    {
        const float wj = Wp[tid], bj = bp[tid];
        #pragma unroll 4
        for (int tt = 0; tt < CT; ++tt)
            sin_l[tt*SINSTRIDE + tid] = __sinf(tv_l[tt]*wj + bj);
    }
    __syncthreads();

    // phase 2: scores for (t, h0) and (t, h0+4); sin via float4 row reads
    const int t = tid & 63, h0 = tid >> 6;
    const float tv = tv_l[t];
    float fv[IN_DIM];
    #pragma unroll
    for (int i = 0; i < IN_DIM; ++i) fv[i] = f_l[t*9 + i];
    const float dec = __expf(-td*fabsf(tl - tv));
    float sc[2];
    {
        float acc0 = 0.f, acc1 = 0.f;
        const float4* srow = (const float4*)(sin_l + t*SINSTRIDE);
        const float4* kq0 = (const float4*)&kqh[h0][0];
        const float4* kq1 = (const float4*)&kqh[h0+4][0];
        #pragma unroll 4
        for (int j4 = 0; j4 < 64; ++j4) {
            const float4 sv = srow[j4];
            const float4 ka = kq0[j4], kb = kq1[j4];
            acc0 += sv.x*ka.x + sv.y*ka.y + sv.z*ka.z + sv.w*ka.w;
            acc1 += sv.x*kb.x + sv.y*kb.y + sv.z*kb.z + sv.w*kb.w;
        }
        #pragma unroll
        for (int p = 0; p < 2; ++p) {
            const int h = h0 + p*4;
            float base = cf[h*12+8] + tv*cf[h*12+9];
            #pragma unroll
            for (int i = 0; i < IN_DIM; ++i) base += fv[i]*cf[h*12+i];
            sc[p] = (base + ((p == 0) ? acc0 : acc1))*0.125f*dec;
        }
    }
    // phase 3: per-wave (= per (h,chunk)) local softmax stats
    #pragma unroll
    for (int p = 0; p < 2; ++p) {
        const int h = h0 + p*4;
        float m = sc[p];
        #pragma unroll
        for (int off = 32; off >= 1; off >>= 1) m = fmaxf(m, __shfl_xor(m, off, 64));
        const float w = __expf(sc[p] - m);
        float Z = w, ta = w*tv;
        float fa[IN_DIM];
        #pragma unroll
        for (int i = 0; i < IN_DIM; ++i) fa[i] = w*fv[i];
        #pragma unroll
        for (int off = 32; off >= 1; off >>= 1) {
            Z  += __shfl_xor(Z,  off, 64);
            ta += __shfl_xor(ta, off, 64);
            #pragma unroll
            for (int i = 0; i < IN_DIM; ++i) fa[i] += __shfl_xor(fa[i], off, 64);
        }
        w_l[t*8 + h] = w;
        if (t == 0) {
            float* pm = ws + WS_PM + ((b*NCHUNK + c)*HEADS + h)*16;
            pm[0] = m; pm[1] = Z; pm[2] = ta;
            #pragma unroll
            for (int i = 0; i < IN_DIM; ++i) pm[3+i] = fa[i];
        }
    }
    __syncthreads();
    // phase 4: S_c[h][j] = sum_t w[t][h] * sin[t][j]
    {
        const int j = tid;
        float accS[HEADS] = {0.f,0.f,0.f,0.f,0.f,0.f,0.f,0.f};
        const float4* wv4 = (const float4*)w_l;
        #pragma unroll 4
        for (int tt = 0; tt < CT; ++tt) {
            const float sv = sin_l[tt*SINSTRIDE + j];
            const float4 wa = wv4[tt*2], wb = wv4[tt*2+1];
            accS[0] += wa.x*sv; accS[1] += wa.y*sv; accS[2] += wa.z*sv; accS[3] += wa.w*sv;
            accS[4] += wb.x*sv; accS[5] += wb.y*sv; accS[6] += wb.z*sv; accS[7] += wb.w*sv;
        }
        const int base = WS_PS + ((b*NCHUNK + c)*HEADS)*256 + j;
        #pragma unroll
        for (int h = 0; h < HEADS; ++h) ws[base + h*256] = accS[h];
    }
}

// K3: per (b,h), 512 thr: flash merge -> wx -> Wv gemv (oh chunk) -> Wo partial
__global__ __launch_bounds__(512) void k_ohw(
    const float* __restrict__ Wf, const float* __restrict__ bf,
    const float* __restrict__ Wl, const float* __restrict__ bl,
    const float* __restrict__ Wv, const float* __restrict__ bv,
    const float* __restrict__ Wo, float* __restrict__ ws)
{
    const int h = blockIdx.x;
    const int b = blockIdx.y;
    const int tid = threadIdx.x;
    __shared__ float pmL[NCHUNK][12];
    __shared__ float al[NCHUNK];
    __shared__ float cfL[10];
    __shared__ float wx[EMB];
    __shared__ float red[8][64];
    __shared__ __align__(16) float oh_c[HDIM];

    if (tid < NCHUNK*11)
        pmL[tid/11][tid%11] = ws[WS_PM + ((b*NCHUNK + tid/11)*HEADS + h)*16 + tid%11];
    __syncthreads();
    float m = pmL[0][0];
    #pragma unroll 8
    for (int c = 1; c < NCHUNK; ++c) m = fmaxf(m, pmL[c][0]);
    if (tid < NCHUNK) al[tid] = __expf(pmL[tid][0] - m);
    __syncthreads();
    float Z = 0.f;
    #pragma unroll 8
    for (int c = 0; c < NCHUNK; ++c) Z += al[c]*pmL[c][1];
    const float inv = 1.f/Z;
    if (tid < 9) {
        const int k = (tid == 8) ? 2 : 3 + tid;   // ta at [2], fa_i at [3+i]
        float acc = 0.f;
        #pragma unroll 8
        for (int c = 0; c < NCHUNK; ++c) acc += al[c]*pmL[c][k];
        cfL[(tid == 8) ? 8 : tid] = acc*inv;
    }
    __syncthreads();
    // wx assembly: e = tid (0..511)
    {
        const int e = tid;
        float val = bf[e];
        #pragma unroll
        for (int i = 0; i < IN_DIM; ++i) val += cfL[i]*Wf[i*EMB + e];
        if (e < HALF) {
            val += cfL[8]*Wl[e] + bl[e];
        } else {
            const int j = e - HALF;
            float acc = 0.f;
            #pragma unroll 8
            for (int c = 0; c < NCHUNK; ++c)
                acc += al[c]*ws[WS_PS + ((b*NCHUNK + c)*HEADS + h)*256 + j];
            val += acc*inv;
        }
        wx[e] = val;
    }
    __syncthreads();
    // Wv gemv for this head's 64 cols (8-way split-K)
    {
        const int eo = tid & 63, jq = tid >> 6;
        const int e = h*HDIM + eo;
        float acc = 0.f;
        #pragma unroll 8
        for (int j = jq*64; j < jq*64 + 64; ++j)
            acc += wx[j]*Wv[j*EMB + e];
        red[jq][eo] = acc;
    }
    __syncthreads();
    if (tid < 64) {
        float s = 0.f;
        #pragma unroll
        for (int q = 0; q < 8; ++q) s += red[q][tid];
        oh_c[tid] = s + bv[h*HDIM + tid];
    }
    __syncthreads();
    // Wo partial: pop[e] = sum_{d<64} oh_c[d] * Wo[(h*64+d)*EMB + e]
    {
        const int e = tid;
        float acc = 0.f;
        #pragma unroll 8
        for (int d = 0; d < HDIM; ++d)
            acc += oh_c[d]*Wo[(h*HDIM + d)*EMB + e];
        ws[WS_POP + (b*HEADS + h)*EMB + e] = acc;
    }
}

// K4: per b: op = sum_h pop + bo -> hh = relu(op @ W1 + b1) -> logits
__global__ __launch_bounds__(1024) void k_tail2(
    const float* __restrict__ bo,
    const float* __restrict__ W1, const float* __restrict__ b1,
    const float* __restrict__ W2, const float* __restrict__ b2,
    const float* __restrict__ ws, float* __restrict__ out)
{
    const int b = blockIdx.x;
    const int tid = threadIdx.x;
    __shared__ float opL[EMB];
    __shared__ float red[4][HALF];
    __shared__ float hhL[HALF];
    __shared__ float red3[4][3];

    if (tid < EMB) {
        float acc = bo[tid];
        #pragma unroll
        for (int h = 0; h < HEADS; ++h)
            acc += ws[WS_POP + (b*HEADS + h)*EMB + tid];
        opL[tid] = acc;
    }
    __syncthreads();
    {
        const int mm = tid & 255, jq = tid >> 8;
        float acc = 0.f;
        #pragma unroll 8
        for (int j = jq*128; j < jq*128 + 128; ++j)
            acc += opL[j]*W1[j*HALF + mm];
        red[jq][mm] = acc;
    }
    __syncthreads();
    if (tid < HALF)
        hhL[tid] = fmaxf(red[0][tid]+red[1][tid]+red[2][tid]+red[3][tid] + b1[tid], 0.f);
    __syncthreads();
    if (tid < HALF) {
        const float hv = hhL[tid];
        float p0 = hv*W2[tid*NCLS + 0];
        float p1 = hv*W2[tid*NCLS + 1];
        float p2 = hv*W2[tid*NCLS + 2];
        #pragma unroll
        for (int off = 32; off >= 1; off >>= 1) {
            p0 += __shfl_xor(p0, off, 64);
            p1 += __shfl_xor(p1, off, 64);
            p2 += __shfl_xor(p2, off, 64);
        }
        const int wid = tid >> 6;
        if ((tid & 63) == 0) { red3[wid][0] = p0; red3[wid][1] = p1; red3[wid][2] = p2; }
    }
    __syncthreads();
    if (tid < NCLS)
        out[b*NCLS + tid] = red3[0][tid]+red3[1][tid]+red3[2][tid]+red3[3][tid] + b2[tid];
}

extern "C" void kernel_launch(void* const* d_in, const int* in_sizes, int n_in,
                              void* d_out, int out_size, void* d_ws, size_t ws_size,
                              hipStream_t stream)
{
    const float* feat = (const float*)d_in[0];
    const float* ts   = (const float*)d_in[1];
    const float* Wf = (const float*)d_in[2];
    const float* bf = (const float*)d_in[3];
    const float* Wl = (const float*)d_in[4];
    const float* bl = (const float*)d_in[5];
    const float* Wp = (const float*)d_in[6];
    const float* bp = (const float*)d_in[7];
    const float* Wq = (const float*)d_in[8];
    const float* bq = (const float*)d_in[9];
    const float* Wk = (const float*)d_in[10];
    const float* bk = (const float*)d_in[11];
    const float* Wv = (const float*)d_in[12];
    const float* bv = (const float*)d_in[13];
    const float* Wo = (const float*)d_in[14];
    const float* bo = (const float*)d_in[15];
    const float* td = (const float*)d_in[16];
    const float* W1 = (const float*)d_in[17];
    const float* b1 = (const float*)d_in[18];
    const float* W2 = (const float*)d_in[19];
    const float* b2 = (const float*)d_in[20];
    float* ws = (float*)d_ws;
    float* out = (float*)d_out;

    hipLaunchKernelGGL(k_head,  dim3(HEADS, B),  dim3(256),  0, stream,
                       feat, ts, Wf, bf, Wl, bl, Wp, bp, Wq, bq, Wk, bk, ws);
    hipLaunchKernelGGL(k_part,  dim3(NCHUNK, B), dim3(256),  0, stream,
                       feat, ts, Wp, bp, td, ws);
    hipLaunchKernelGGL(k_ohw,   dim3(HEADS, B),  dim3(512),  0, stream,
                       Wf, bf, Wl, bl, Wv, bv, Wo, ws);
    hipLaunchKernelGGL(k_tail2, dim3(B),         dim3(1024), 0, stream,
                       bo, W1, b1, W2, b2, ws, out);
}